// Round 6
// baseline (3420.436 us; speedup 1.0000x reference)
//
#include <hip/hip_runtime.h>
#include <math.h>

// Problem dims (fixed by reference)
#define SEQ   128
#define BATCH 64
#define HD    1024
#define NG    4096
#define TOUT  32
#define NE    65536    // BATCH*HD

typedef __attribute__((ext_vector_type(8))) short short8;
typedef __attribute__((ext_vector_type(4))) float f32x4;

#define MFMA16(a,b,c) __builtin_amdgcn_mfma_f32_16x16x32_bf16((a),(b),(c),0,0,0)

__device__ __forceinline__ ushort bf16_rne(float x) {
    union { float f; unsigned u; } v; v.f = x;
    unsigned r = v.u + 0x7FFF + ((v.u >> 16) & 1);
    return (ushort)(r >> 16);
}

// ---- device-coherent (agent-scope, L3-point) accesses: sc0|sc1, no fences ----
__device__ __forceinline__ unsigned long long cload64(const void* p) {
    return __hip_atomic_load((const unsigned long long*)p, __ATOMIC_RELAXED,
                             __HIP_MEMORY_SCOPE_AGENT);
}
__device__ __forceinline__ void cstore32(void* p, unsigned v) {
    __hip_atomic_store((unsigned*)p, v, __ATOMIC_RELAXED, __HIP_MEMORY_SCOPE_AGENT);
}
__device__ __forceinline__ void cstore64(void* p, unsigned long long v) {
    __hip_atomic_store((unsigned long long*)p, v, __ATOMIC_RELAXED,
                       __HIP_MEMORY_SCOPE_AGENT);
}

union Q2 { unsigned long long q[2]; short8 v8; };
union QF { unsigned long long q; float f[2]; };

// Barrier memory map (u32 index into bar):
//   grp[g]     @ g*64        (g = 0..7, 256B apart)
//   root       @ 512
//   release[b] @ 1024 + b*16 (b = 0..255, 64B apart)
// total 5120 u32 = 20 KB
#define BAR_WORDS 5120

// ---------------------------------------------------------------------------
// fp32 -> bf16 (RNE), 4 elems/thread; n % 1024 == 0
// ---------------------------------------------------------------------------
__global__ __launch_bounds__(256) void cvt_bf16(
    const float* __restrict__ src, ushort* __restrict__ dst, int n)
{
    int i = (blockIdx.x * 256 + threadIdx.x) * 4;
    if (i < n) {
        float4 v = *(const float4*)(src + i);
        ushort4 o;
        o.x = bf16_rne(v.x); o.y = bf16_rne(v.y);
        o.z = bf16_rne(v.z); o.w = bf16_rne(v.w);
        *(ushort4*)(dst + i) = o;
    }
}

// prep: h0 -> bf16; zero the whole barrier region (re-poisoned every launch;
// kernel-end L2 writeback publishes these before lstm_coop starts).
__global__ __launch_bounds__(256) void prep(
    const float* __restrict__ h0, ushort* __restrict__ h0b, unsigned* __restrict__ bar)
{
    int i = blockIdx.x * 256 + threadIdx.x;
    h0b[i] = bf16_rne(h0[i]);
    if (blockIdx.x == 0)
        for (int k = threadIdx.x; k < BAR_WORDS; k += 256) bar[k] = 0u;
}

// ---------------------------------------------------------------------------
// Fence-free grid barrier, contention-free release:
// arrival = 8x32 atomic tree (separate lines); finisher's wave 0 fans the
// epoch out to 256 per-block release lines; each leader spins on its OWN line.
// ---------------------------------------------------------------------------
__device__ __forceinline__ void bar_sync(unsigned* bar, int blk, unsigned epoch) {
    asm volatile("s_waitcnt vmcnt(0) lgkmcnt(0)" ::: "memory");
    __syncthreads();
    if (threadIdx.x < 64) {
        bool fin = false;
        if (threadIdx.x == 0) {
            unsigned* grp = bar + (blk >> 5) * 64;
            if (__hip_atomic_fetch_add(grp, 1u, __ATOMIC_RELAXED,
                                       __HIP_MEMORY_SCOPE_AGENT) == 31u) {
                __hip_atomic_store(grp, 0u, __ATOMIC_RELAXED, __HIP_MEMORY_SCOPE_AGENT);
                if (__hip_atomic_fetch_add(bar + 512, 1u, __ATOMIC_RELAXED,
                                           __HIP_MEMORY_SCOPE_AGENT) == 7u) {
                    __hip_atomic_store(bar + 512, 0u, __ATOMIC_RELAXED,
                                       __HIP_MEMORY_SCOPE_AGENT);
                    fin = true;
                }
            }
        }
        if (__ballot(fin) != 0ull) {
            #pragma unroll
            for (int i = 0; i < 4; i++)
                cstore32(bar + 1024 + (threadIdx.x + i * 64) * 16, epoch);
        }
        if (threadIdx.x == 0) {
            while (__hip_atomic_load(bar + 1024 + blk * 16, __ATOMIC_RELAXED,
                                     __HIP_MEMORY_SCOPE_AGENT) < epoch)
                __builtin_amdgcn_s_sleep(1);
        }
    }
    __syncthreads();
}

// ---------------------------------------------------------------------------
// One LSTM cell step for block (bg,ug): gates[16b x 64cols] where wave = gate
// type, col l15 = unit. h staged to LDS via coherent loads; x normal (encode)
// or coherent (decode); W normal loads (L2-resident). c in a register.
// ---------------------------------------------------------------------------
template<bool XCOH>
__device__ __forceinline__ void cell_step(
    const ushort* __restrict__ xsrc, const ushort* __restrict__ hcur,
    ushort* __restrict__ hnxt,
    const ushort* __restrict__ Wih, const ushort* __restrict__ Whh,
    ushort* hs, float* gbuf, int bg, int ug,
    float bs0, float bs1, float bs2, float bs3,
    float& c_reg, bool fin, float* __restrict__ fin_out)
{
    const int tid = threadIdx.x;
    const int wave = tid >> 6, lane = tid & 63;
    const int l15 = lane & 15, q8 = (lane >> 4) * 8, r0 = (lane >> 4) * 4;

    // stage h tile (16 rows x 1024) -> hs[row*1032+col], coherent 8B loads
    #pragma unroll
    for (int i = 0; i < 16; i++) {
        int idx = i * 256 + tid;           // qword index (4 ushorts each)
        int flat = idx * 4;
        int row = flat >> 10, col = flat & 1023;
        *(unsigned long long*)&hs[row * 1032 + col] =
            cload64(hcur + ((size_t)(bg * 16 + row) << 10) + col);
    }
    __syncthreads();

    const ushort* xp  = xsrc + ((size_t)(bg * 16 + l15) << 10) + q8;
    const ushort* wip = Wih + ((size_t)(wave * 1024 + ug * 16 + l15) << 10) + q8;
    const ushort* whp = Whh + ((size_t)(wave * 1024 + ug * 16 + l15) << 10) + q8;
    const ushort* hp  = hs + l15 * 1032 + q8;

    f32x4 acc0 = {0.f,0.f,0.f,0.f}, acc1 = {0.f,0.f,0.f,0.f};
    #pragma unroll 4
    for (int kk = 0; kk < 1024; kk += 64) {
        short8 xa0, xa1;
        if (XCOH) {
            Q2 t0; t0.q[0] = cload64(xp + kk);      t0.q[1] = cload64(xp + kk + 4);  xa0 = t0.v8;
            Q2 t1; t1.q[0] = cload64(xp + kk + 32); t1.q[1] = cload64(xp + kk + 36); xa1 = t1.v8;
        } else {
            xa0 = *(const short8*)(xp + kk);
            xa1 = *(const short8*)(xp + kk + 32);
        }
        short8 ha0 = *(const short8*)(hp + kk);
        short8 ha1 = *(const short8*)(hp + kk + 32);
        short8 wi0 = *(const short8*)(wip + kk);
        short8 wi1 = *(const short8*)(wip + kk + 32);
        short8 wh0 = *(const short8*)(whp + kk);
        short8 wh1 = *(const short8*)(whp + kk + 32);
        acc0 = MFMA16(xa0, wi0, acc0);
        acc0 = MFMA16(ha0, wh0, acc0);
        acc1 = MFMA16(xa1, wi1, acc1);
        acc1 = MFMA16(ha1, wh1, acc1);
    }
    f32x4 acc = acc0 + acc1;
    #pragma unroll
    for (int r = 0; r < 4; r++)
        gbuf[(r0 + r) * 68 + wave * 16 + l15] = acc[r];   // row=batch, col=type*16+unit
    __syncthreads();

    const int b = tid >> 4, u = tid & 15;
    float ig = gbuf[b * 68 + u]      + bs0;
    float fg = gbuf[b * 68 + 16 + u] + bs1;
    float gg = gbuf[b * 68 + 32 + u] + bs2;
    float og = gbuf[b * 68 + 48 + u] + bs3;
    float si = 1.f / (1.f + expf(-ig));
    float sf = 1.f / (1.f + expf(-fg));
    float so = 1.f / (1.f + expf(-og));
    float tg = tanhf(gg);
    float cn = sf * c_reg + si * tg;
    c_reg = cn;
    float hn = so * tanhf(cn);

    // pack 2 units -> 1 dword, coherent store
    ushort hb = bf16_rne(hn);
    unsigned hi = (unsigned)(ushort)__shfl_down((int)hb, 1);
    const size_t gidx = ((size_t)(bg * 16 + b) << 10) + ug * 16 + u;
    if ((u & 1) == 0)
        cstore32((void*)(hnxt + gidx), (unsigned)hb | (hi << 16));
    if (fin) {
        fin_out[gidx]      = hn;
        fin_out[NE + gidx] = cn;
    }
}

// ---------------------------------------------------------------------------
// Projection (blocks 0..63): block p owns out-cols [16p,16p+16).
// h read coherent (each wave reads distinct rows), W_out normal, y coherent.
// ---------------------------------------------------------------------------
__device__ __forceinline__ void proj_step(
    const ushort* __restrict__ hcur, const ushort* __restrict__ Wout,
    float* __restrict__ y, int p, float bout)
{
    const int tid = threadIdx.x;
    const int wave = tid >> 6, lane = tid & 63;
    const int l15 = lane & 15, q8 = (lane >> 4) * 8, r0 = (lane >> 4) * 4;

    const ushort* hp = hcur + ((size_t)(wave * 16 + l15) << 10) + q8;
    const ushort* wp = Wout + ((size_t)(p * 16 + l15) << 10) + q8;

    f32x4 acc0 = {0.f,0.f,0.f,0.f}, acc1 = {0.f,0.f,0.f,0.f};
    #pragma unroll 4
    for (int kk = 0; kk < 1024; kk += 64) {
        Q2 t0; t0.q[0] = cload64(hp + kk);      t0.q[1] = cload64(hp + kk + 4);
        Q2 t1; t1.q[0] = cload64(hp + kk + 32); t1.q[1] = cload64(hp + kk + 36);
        short8 w0 = *(const short8*)(wp + kk);
        short8 w1 = *(const short8*)(wp + kk + 32);
        acc0 = MFMA16(t0.v8, w0, acc0);
        acc1 = MFMA16(t1.v8, w1, acc1);
    }
    f32x4 acc = acc0 + acc1;
    #pragma unroll
    for (int r = 0; r < 4; r++) {
        union { float f; unsigned u; } cv; cv.f = acc[r] + bout;
        cstore32(y + (size_t)(wave * 16 + r0 + r) * 1024 + p * 16 + l15, cv.u);
    }
}

// ---------------------------------------------------------------------------
// Log-softmax (blocks 0..63): block b = batch row. y coherent in, fp32 out
// (normal store) + bf16 xd (coherent store).
// ---------------------------------------------------------------------------
__device__ __forceinline__ void softmax_step(
    const float* __restrict__ y, int b, float* __restrict__ outp,
    ushort* __restrict__ xd, float* red)
{
    const int tid = threadIdx.x;
    QF a, c;
    a.q = cload64(y + (size_t)b * 1024 + tid * 4);
    c.q = cload64(y + (size_t)b * 1024 + tid * 4 + 2);
    float v0 = a.f[0], v1 = a.f[1], v2 = c.f[0], v3 = c.f[1];

    red[tid] = fmaxf(fmaxf(v0, v1), fmaxf(v2, v3));
    __syncthreads();
    for (int st = 128; st > 0; st >>= 1) {
        if (tid < st) red[tid] = fmaxf(red[tid], red[tid + st]);
        __syncthreads();
    }
    float m = red[0];
    __syncthreads();
    red[tid] = expf(v0 - m) + expf(v1 - m) + expf(v2 - m) + expf(v3 - m);
    __syncthreads();
    for (int st = 128; st > 0; st >>= 1) {
        if (tid < st) red[tid] += red[tid + st];
        __syncthreads();
    }
    float lse = m + logf(red[0]);

    float4 o = make_float4(v0 - lse, v1 - lse, v2 - lse, v3 - lse);
    *(float4*)(outp + (size_t)b * 1024 + tid * 4) = o;   // normal: host-read only
    unsigned lo = (unsigned)bf16_rne(o.x) | ((unsigned)bf16_rne(o.y) << 16);
    unsigned hi = (unsigned)bf16_rne(o.z) | ((unsigned)bf16_rne(o.w) << 16);
    cstore64(xd + (size_t)b * 1024 + tid * 4,
             (unsigned long long)lo | ((unsigned long long)hi << 32));
}

// ---------------------------------------------------------------------------
// Persistent cooperative LSTM: 256 blocks (1/CU), fence-free fast barriers.
// ---------------------------------------------------------------------------
__global__ __launch_bounds__(256, 1) void lstm_coop(
    const ushort* __restrict__ Wih, const ushort* __restrict__ Whh,
    const ushort* __restrict__ Wout, const ushort* __restrict__ Xbf,
    ushort* __restrict__ hA, ushort* __restrict__ hB, ushort* __restrict__ xd,
    float* __restrict__ y, unsigned* __restrict__ bar,
    const float* __restrict__ b_ih, const float* __restrict__ b_hh,
    const float* __restrict__ b_out, const float* __restrict__ c0,
    float* __restrict__ out)
{
    __shared__ ushort hs[16 * 1032];     // h tile, pad 8 -> conflict-free b128
    __shared__ float gbuf[16 * 68];      // gate tile / softmax scratch

    const int blk = blockIdx.x;
    const int bg = blk >> 6, ug = blk & 63;   // blk%8 = ug%8 -> W slice pinned per XCD
    const int tid = threadIdx.x;
    const int b = tid >> 4, u = tid & 15;
    const int lane = tid & 63, l15 = lane & 15;

    const int gi = ug * 16 + u;
    const float bs0 = b_ih[gi]        + b_hh[gi];
    const float bs1 = b_ih[1024 + gi] + b_hh[1024 + gi];
    const float bs2 = b_ih[2048 + gi] + b_hh[2048 + gi];
    const float bs3 = b_ih[3072 + gi] + b_hh[3072 + gi];
    float c_reg = c0[((size_t)(bg * 16 + b) << 10) + gi];
    const float bout = (blk < 64) ? b_out[blk * 16 + l15] : 0.f;

    ushort* hcur = hA;
    ushort* hnxt = hB;
    unsigned ep = 1;

    // ---- encode: 128 steps, 1 barrier each ----
    for (int t = 0; t < SEQ; t++) {
        cell_step<false>(Xbf + (size_t)t * NE, hcur, hnxt, Wih, Whh,
                         hs, gbuf, bg, ug, bs0, bs1, bs2, bs3,
                         c_reg, false, nullptr);
        bar_sync(bar, blk, ep); ep++;
        ushort* tmp = hcur; hcur = hnxt; hnxt = tmp;
    }

    // ---- out0 ----
    if (blk < 64) proj_step(hcur, Wout, y, blk, bout);
    bar_sync(bar, blk, ep); ep++;
    if (blk < 64) softmax_step(y, blk, out, xd, gbuf);
    bar_sync(bar, blk, ep); ep++;

    // ---- decode: 31 steps, 3 barriers each ----
    for (int d = 1; d < TOUT; d++) {
        cell_step<true>(xd, hcur, hnxt, Wih, Whh, hs, gbuf, bg, ug,
                        bs0, bs1, bs2, bs3, c_reg,
                        d == TOUT - 1, out + (size_t)TOUT * NE);
        bar_sync(bar, blk, ep); ep++;
        ushort* tmp = hcur; hcur = hnxt; hnxt = tmp;
        if (blk < 64) proj_step(hcur, Wout, y, blk, bout);
        bar_sync(bar, blk, ep); ep++;
        if (blk < 64) softmax_step(y, blk, out + (size_t)d * NE, xd, gbuf);
        bar_sync(bar, blk, ep); ep++;
    }
}

// ---------------------------------------------------------------------------
extern "C" void kernel_launch(void* const* d_in, const int* in_sizes, int n_in,
                              void* d_out, int out_size, void* d_ws, size_t ws_size,
                              hipStream_t stream)
{
    const float* input = (const float*)d_in[0];   // [128,64,1024]
    const float* h0    = (const float*)d_in[1];
    const float* c0    = (const float*)d_in[2];
    const float* W_ih  = (const float*)d_in[3];   // [4096,1024]
    const float* W_hh  = (const float*)d_in[4];
    const float* b_ih  = (const float*)d_in[5];
    const float* b_hh  = (const float*)d_in[6];
    const float* W_out = (const float*)d_in[7];   // [1024,1024]
    const float* b_out = (const float*)d_in[8];
    float* out = (float*)d_out;                   // [32,64,1024] + h + c

    char* w = (char*)d_ws;
    ushort*   Wih_bf  = (ushort*)(w + 0);          //  8,388,608 B
    ushort*   Whh_bf  = (ushort*)(w + 8388608);    //  8,388,608 B
    ushort*   Wout_bf = (ushort*)(w + 16777216);   //  2,097,152 B
    ushort*   Xbf     = (ushort*)(w + 18874368);   // 16,777,216 B
    ushort*   hA      = (ushort*)(w + 35651584);   //    131,072 B
    ushort*   hB      = (ushort*)(w + 35782656);   //    131,072 B
    ushort*   xd      = (ushort*)(w + 35913728);   //    131,072 B
    float*    y       = (float*) (w + 36044800);   //    262,144 B
    unsigned* bar     = (unsigned*)(w + 36306944); //     20,480 B

    cvt_bf16<<<dim3(4096), dim3(256), 0, stream>>>(W_ih,  Wih_bf,  NG * HD);
    cvt_bf16<<<dim3(4096), dim3(256), 0, stream>>>(W_hh,  Whh_bf,  NG * HD);
    cvt_bf16<<<dim3(1024), dim3(256), 0, stream>>>(W_out, Wout_bf, HD * HD);
    cvt_bf16<<<dim3(8192), dim3(256), 0, stream>>>(input, Xbf, SEQ * NE);
    prep<<<dim3(256), dim3(256), 0, stream>>>(h0, hA, bar);

    const ushort* a0 = Wih_bf;  const ushort* a1 = Whh_bf;
    const ushort* a2 = Wout_bf; const ushort* a3 = Xbf;
    ushort* a4 = hA; ushort* a5 = hB; ushort* a6 = xd;
    float* a7 = y; unsigned* a8 = bar;
    const float* a9 = b_ih; const float* a10 = b_hh; const float* a11 = b_out;
    const float* a12 = c0;  float* a13 = out;
    void* args[] = {&a0, &a1, &a2, &a3, &a4, &a5, &a6, &a7, &a8,
                    &a9, &a10, &a11, &a12, &a13};
    hipLaunchCooperativeKernel((const void*)lstm_coop, dim3(256), dim3(256),
                               args, 0, stream);
}

// Round 7
// 1956.425 us; speedup vs baseline: 1.7483x; 1.7483x over previous
//
#include <hip/hip_runtime.h>
#include <math.h>

// Problem dims (fixed by reference)
#define SEQ   128
#define BATCH 64
#define HD    1024
#define NG    4096
#define TOUT  32
#define NE    65536    // BATCH*HD
#define MROWS 8192     // SEQ*BATCH

typedef __attribute__((ext_vector_type(8))) short    short8;
typedef __attribute__((ext_vector_type(4))) float    f32x4;
typedef __attribute__((ext_vector_type(4))) int      i32x4;
typedef __attribute__((ext_vector_type(4))) _Float16 f16x4;

#define MFMA16(a,b,c) __builtin_amdgcn_mfma_f32_16x16x32_bf16((a),(b),(c),0,0,0)

__device__ __forceinline__ ushort bf16_rne(float x) {
    union { float f; unsigned u; } v; v.f = x;
    unsigned r = v.u + 0x7FFF + ((v.u >> 16) & 1);
    return (ushort)(r >> 16);
}

// ---- device-coherent (agent-scope, L3-point) accesses, no fences ----
__device__ __forceinline__ unsigned long long cload64(const void* p) {
    return __hip_atomic_load((const unsigned long long*)p, __ATOMIC_RELAXED,
                             __HIP_MEMORY_SCOPE_AGENT);
}
__device__ __forceinline__ void cstore32(void* p, unsigned v) {
    __hip_atomic_store((unsigned*)p, v, __ATOMIC_RELAXED, __HIP_MEMORY_SCOPE_AGENT);
}
__device__ __forceinline__ void cstore64(void* p, unsigned long long v) {
    __hip_atomic_store((unsigned long long*)p, v, __ATOMIC_RELAXED,
                       __HIP_MEMORY_SCOPE_AGENT);
}

union QF { unsigned long long q; float f[2]; };
#define BAR_WORDS 5120

// ---------------------------------------------------------------------------
// fp32 -> bf16 (RNE), 4 elems/thread; n % 1024 == 0
// ---------------------------------------------------------------------------
__global__ __launch_bounds__(256) void cvt_bf16(
    const float* __restrict__ src, ushort* __restrict__ dst, int n)
{
    int i = (blockIdx.x * 256 + threadIdx.x) * 4;
    if (i < n) {
        float4 v = *(const float4*)(src + i);
        ushort4 o;
        o.x = bf16_rne(v.x); o.y = bf16_rne(v.y);
        o.z = bf16_rne(v.z); o.w = bf16_rne(v.w);
        *(ushort4*)(dst + i) = o;
    }
}

// prep: h0 -> bf16; zero barrier region (ws is re-poisoned every launch).
__global__ __launch_bounds__(256) void prep(
    const float* __restrict__ h0, ushort* __restrict__ h0b, unsigned* __restrict__ bar)
{
    int i = blockIdx.x * 256 + threadIdx.x;
    h0b[i] = bf16_rne(h0[i]);
    if (blockIdx.x == 0)
        for (int k = threadIdx.x; k < BAR_WORDS; k += 256) bar[k] = 0u;
}

// ---------------------------------------------------------------------------
// XgT GEMM: XgT[gcol][m] = sum_k bf16(X[m][k]) * Wih[gcol][k]   (fp16 out)
// X fp32 [8192][1024], Wih bf16 [4096][1024].  128x128 tiles, 2x2 wave frags.
// grid (4096/128, 8192/128) = (32, 64), block 256.
// ---------------------------------------------------------------------------
__global__ __launch_bounds__(256) void gemm_xgt(
    const float* __restrict__ X, const ushort* __restrict__ Wih,
    _Float16* __restrict__ XgT)
{
    const int wave = threadIdx.x >> 6, lane = threadIdx.x & 63;
    const int l15 = lane & 15, q8 = (lane >> 4) * 8, r0 = (lane >> 4) * 4;
    const int wr = wave >> 1, wc = wave & 1;
    const int m0 = blockIdx.y * 128 + wr * 64;
    const int n0 = blockIdx.x * 128 + wc * 64;

    const float*  ap[4];
    const ushort* bp[4];
    #pragma unroll
    for (int f = 0; f < 4; f++) {
        ap[f] = X   + (size_t)(m0 + f * 16 + l15) * 1024 + q8;
        bp[f] = Wih + (size_t)(n0 + f * 16 + l15) * 1024 + q8;
    }

    f32x4 acc[4][4];
    #pragma unroll
    for (int f = 0; f < 4; f++)
        #pragma unroll
        for (int g = 0; g < 4; g++)
            acc[f][g] = (f32x4){0.f, 0.f, 0.f, 0.f};

    for (int kk = 0; kk < 1024; kk += 32) {
        short8 a[4], b[4];
        #pragma unroll
        for (int f = 0; f < 4; f++) {
            float4 x0 = *(const float4*)(ap[f] + kk);
            float4 x1 = *(const float4*)(ap[f] + kk + 4);
            short8 av;
            av[0] = (short)bf16_rne(x0.x); av[1] = (short)bf16_rne(x0.y);
            av[2] = (short)bf16_rne(x0.z); av[3] = (short)bf16_rne(x0.w);
            av[4] = (short)bf16_rne(x1.x); av[5] = (short)bf16_rne(x1.y);
            av[6] = (short)bf16_rne(x1.z); av[7] = (short)bf16_rne(x1.w);
            a[f] = av;
            b[f] = *(const short8*)(bp[f] + kk);
        }
        #pragma unroll
        for (int f = 0; f < 4; f++)
            #pragma unroll
            for (int g = 0; g < 4; g++)
                acc[f][g] = MFMA16(a[f], b[g], acc[f][g]);
    }

    #pragma unroll
    for (int f = 0; f < 4; f++) {
        const int mbase = m0 + f * 16 + r0;
        #pragma unroll
        for (int g = 0; g < 4; g++) {
            const int gcol = n0 + g * 16 + l15;
            *(f16x4*)(XgT + (size_t)gcol * MROWS + mbase) =
                __builtin_convertvector(acc[f][g], f16x4);
        }
    }
}

// ---------------------------------------------------------------------------
// Fence-free grid barrier (round-6 design: 8x32 arrival tree + per-block
// release lines; leader spins on its own 64B-spaced word).
// ---------------------------------------------------------------------------
__device__ __forceinline__ void bar_sync(unsigned* bar, int blk, unsigned epoch) {
    asm volatile("s_waitcnt vmcnt(0) lgkmcnt(0)" ::: "memory");
    __syncthreads();
    if (threadIdx.x < 64) {
        bool fin = false;
        if (threadIdx.x == 0) {
            unsigned* grp = bar + (blk >> 5) * 64;
            if (__hip_atomic_fetch_add(grp, 1u, __ATOMIC_RELAXED,
                                       __HIP_MEMORY_SCOPE_AGENT) == 31u) {
                __hip_atomic_store(grp, 0u, __ATOMIC_RELAXED, __HIP_MEMORY_SCOPE_AGENT);
                if (__hip_atomic_fetch_add(bar + 512, 1u, __ATOMIC_RELAXED,
                                           __HIP_MEMORY_SCOPE_AGENT) == 7u) {
                    __hip_atomic_store(bar + 512, 0u, __ATOMIC_RELAXED,
                                       __HIP_MEMORY_SCOPE_AGENT);
                    fin = true;
                }
            }
        }
        if (__ballot(fin) != 0ull) {
            #pragma unroll
            for (int i = 0; i < 4; i++)
                cstore32(bar + 1024 + (threadIdx.x + i * 64) * 16, epoch);
        }
        if (threadIdx.x == 0) {
            while (__hip_atomic_load(bar + 1024 + blk * 16, __ATOMIC_RELAXED,
                                     __HIP_MEMORY_SCOPE_AGENT) < epoch)
                __builtin_amdgcn_s_sleep(1);
        }
    }
    __syncthreads();
}

// ---------------------------------------------------------------------------
// Stage a 16-row x 1024-col bf16 tile (32 KB) from global (device-coherent)
// into LDS (pitch 1032) using 16B sc0/sc1 loads: 8 requests per thread,
// one tied waitcnt -> fully pipelined across the wave's vm queue.
// ---------------------------------------------------------------------------
__device__ __forceinline__ void stage16(const ushort* __restrict__ src,
                                        ushort* __restrict__ dst)
{
    const int tid = threadIdx.x;
    i32x4 r0, r1, r2, r3, r4, r5, r6, r7;
#define STG_ADDR(i) (src + (((size_t)((i * 256 + tid) >> 7)) << 10) + (((i * 256 + tid) & 127) * 8))
    asm volatile("global_load_dwordx4 %0, %1, off sc0 sc1" : "=v"(r0) : "v"(STG_ADDR(0)));
    asm volatile("global_load_dwordx4 %0, %1, off sc0 sc1" : "=v"(r1) : "v"(STG_ADDR(1)));
    asm volatile("global_load_dwordx4 %0, %1, off sc0 sc1" : "=v"(r2) : "v"(STG_ADDR(2)));
    asm volatile("global_load_dwordx4 %0, %1, off sc0 sc1" : "=v"(r3) : "v"(STG_ADDR(3)));
    asm volatile("global_load_dwordx4 %0, %1, off sc0 sc1" : "=v"(r4) : "v"(STG_ADDR(4)));
    asm volatile("global_load_dwordx4 %0, %1, off sc0 sc1" : "=v"(r5) : "v"(STG_ADDR(5)));
    asm volatile("global_load_dwordx4 %0, %1, off sc0 sc1" : "=v"(r6) : "v"(STG_ADDR(6)));
    asm volatile("global_load_dwordx4 %0, %1, off sc0 sc1" : "=v"(r7) : "v"(STG_ADDR(7)));
    asm volatile("s_waitcnt vmcnt(0)"
                 : "+v"(r0), "+v"(r1), "+v"(r2), "+v"(r3),
                   "+v"(r4), "+v"(r5), "+v"(r6), "+v"(r7));
#undef STG_ADDR
#define STG_ST(i, rr) { int idx = i * 256 + tid; \
    *(i32x4*)&dst[(idx >> 7) * 1032 + ((idx & 127) * 8)] = rr; }
    STG_ST(0, r0) STG_ST(1, r1) STG_ST(2, r2) STG_ST(3, r3)
    STG_ST(4, r4) STG_ST(5, r5) STG_ST(6, r6) STG_ST(7, r7)
#undef STG_ST
}

// ---------------------------------------------------------------------------
// Persistent cooperative LSTM.  Block (bg = blk>>6, ug = blk&63):
// cell: 16-batch x 16-unit tile, wave = gate type; proj: 16-batch x 16-outcol
// tile with wave split-K; softmax: blocks 0..63, one batch row each.
// ---------------------------------------------------------------------------
__global__ __launch_bounds__(256, 1) void lstm_coop(
    const ushort* __restrict__ Wih, const ushort* __restrict__ Whh,
    const ushort* __restrict__ Wout, const _Float16* __restrict__ XgT,
    ushort* __restrict__ hA, ushort* __restrict__ hB, ushort* __restrict__ xd,
    float* __restrict__ y, unsigned* __restrict__ bar,
    const float* __restrict__ b_ih, const float* __restrict__ b_hh,
    const float* __restrict__ b_out, const float* __restrict__ c0,
    float* __restrict__ out)
{
    __shared__ ushort hs[16 * 1032];   // staged tile (h or x), 33 KB
    __shared__ float  gbuf[1088];      // gate tile / proj partials / softmax red

    const int blk  = blockIdx.x;
    const int bg   = blk >> 6, ug = blk & 63;
    const int tid  = threadIdx.x;
    const int wave = tid >> 6, lane = tid & 63;
    const int l15  = lane & 15, q8 = (lane >> 4) * 8, r0 = (lane >> 4) * 4;
    const int b    = tid >> 4, u = tid & 15;

    const int gi = ug * 16 + u;
    const float bs0 = b_ih[gi]        + b_hh[gi];
    const float bs1 = b_ih[1024 + gi] + b_hh[1024 + gi];
    const float bs2 = b_ih[2048 + gi] + b_hh[2048 + gi];
    const float bs3 = b_ih[3072 + gi] + b_hh[3072 + gi];
    float c_reg = c0[((size_t)(bg * 16 + b) << 10) + gi];

    // per-lane weight fragment pointers (gate col = wave*1024 + ug*16 + l15)
    const ushort* wip = Wih + (((size_t)(wave * 1024 + ug * 16 + l15)) << 10) + q8;
    const ushort* whp = Whh + (((size_t)(wave * 1024 + ug * 16 + l15)) << 10) + q8;
    const ushort* wop = Wout + (((size_t)(ug * 16 + l15)) << 10) + wave * 256 + q8;
    // XgT base for acc-init (fp16, transposed: [gatecol][t*64+batch])
    const _Float16* xgp = XgT + (size_t)(wave * 1024 + ug * 16 + l15) * MROWS
                              + bg * 16 + r0;
    const ushort* hfp = hs + l15 * 1032 + q8;   // LDS fragment base

    ushort* hcur = hA;
    ushort* hnxt = hB;
    unsigned ep = 1;

    // -------- pointwise + h-store (shared by enc/dec cells) --------
    auto pointwise = [&](bool fin) {
        float ig = gbuf[b * 68 + u]      + bs0;
        float fg = gbuf[b * 68 + 16 + u] + bs1;
        float gg = gbuf[b * 68 + 32 + u] + bs2;
        float og = gbuf[b * 68 + 48 + u] + bs3;
        float si = 1.f / (1.f + expf(-ig));
        float sf = 1.f / (1.f + expf(-fg));
        float so = 1.f / (1.f + expf(-og));
        float tg = tanhf(gg);
        float cn = sf * c_reg + si * tg;
        c_reg = cn;
        float hn = so * tanhf(cn);
        ushort hb16 = bf16_rne(hn);
        unsigned hi = (unsigned)(ushort)__shfl_down((int)hb16, 1);
        const size_t gidx = ((size_t)(bg * 16 + b) << 10) + gi;
        if ((u & 1) == 0)
            cstore32((void*)(hnxt + gidx), (unsigned)hb16 | (hi << 16));
        if (fin) {
            out[(size_t)TOUT * NE + gidx]       = hn;
            out[(size_t)(TOUT + 1) * NE + gidx] = cn;
        }
    };

    auto gwrite = [&](f32x4 acc) {
        #pragma unroll
        for (int r = 0; r < 4; r++)
            gbuf[(r0 + r) * 68 + wave * 16 + l15] = acc[r];
    };

    // -------- proj: y[bg rows][ug*16 cols] = h @ Wout^T + b_out --------
    auto proj_step = [&]() {
        stage16(hcur + ((size_t)(bg * 16) << 10), hs);
        __syncthreads();
        const ushort* hpp = hs + l15 * 1032 + wave * 256 + q8;
        f32x4 ac = {0.f, 0.f, 0.f, 0.f};
        #pragma unroll
        for (int kk = 0; kk < 256; kk += 32)
            ac = MFMA16(*(const short8*)(hpp + kk), *(const short8*)(wop + kk), ac);
        #pragma unroll
        for (int r = 0; r < 4; r++)
            gbuf[wave * 256 + (r0 + r) * 16 + l15] = ac[r];
        __syncthreads();
        float v = gbuf[b * 16 + u] + gbuf[256 + b * 16 + u]
                + gbuf[512 + b * 16 + u] + gbuf[768 + b * 16 + u]
                + b_out[ug * 16 + u];
        union { float f; unsigned uu; } cv; cv.f = v;
        cstore32(y + (size_t)(bg * 16 + b) * 1024 + ug * 16 + u, cv.uu);
    };

    // -------- softmax (blocks 0..63): row = blk --------
    auto softmax_step = [&](float* __restrict__ outp) {
        QF a, c;
        a.q = cload64(y + (size_t)blk * 1024 + tid * 4);
        c.q = cload64(y + (size_t)blk * 1024 + tid * 4 + 2);
        float v0 = a.f[0], v1 = a.f[1], v2 = c.f[0], v3 = c.f[1];
        gbuf[tid] = fmaxf(fmaxf(v0, v1), fmaxf(v2, v3));
        __syncthreads();
        for (int st = 128; st > 0; st >>= 1) {
            if (tid < st) gbuf[tid] = fmaxf(gbuf[tid], gbuf[tid + st]);
            __syncthreads();
        }
        float m = gbuf[0];
        __syncthreads();
        gbuf[tid] = expf(v0 - m) + expf(v1 - m) + expf(v2 - m) + expf(v3 - m);
        __syncthreads();
        for (int st = 128; st > 0; st >>= 1) {
            if (tid < st) gbuf[tid] += gbuf[tid + st];
            __syncthreads();
        }
        float lse = m + logf(gbuf[0]);
        float4 o = make_float4(v0 - lse, v1 - lse, v2 - lse, v3 - lse);
        *(float4*)(outp + (size_t)blk * 1024 + tid * 4) = o;
        unsigned lo = (unsigned)bf16_rne(o.x) | ((unsigned)bf16_rne(o.y) << 16);
        unsigned hi = (unsigned)bf16_rne(o.z) | ((unsigned)bf16_rne(o.w) << 16);
        cstore64(xd + (size_t)blk * 1024 + tid * 4,
                 (unsigned long long)lo | ((unsigned long long)hi << 32));
    };

    // ================= encode: 128 steps =================
    for (int t = 0; t < SEQ; t++) {
        f16x4 xg4 = *(const f16x4*)(xgp + (size_t)t * 64);  // issue before stage
        stage16(hcur + ((size_t)(bg * 16) << 10), hs);
        __syncthreads();
        f32x4 acc = __builtin_convertvector(xg4, f32x4);
        #pragma unroll 8
        for (int kk = 0; kk < 1024; kk += 32)
            acc = MFMA16(*(const short8*)(hfp + kk), *(const short8*)(whp + kk), acc);
        gwrite(acc);
        __syncthreads();
        pointwise(false);
        bar_sync(bar, blk, ep); ep++;
        ushort* tmp = hcur; hcur = hnxt; hnxt = tmp;
    }

    // ================= out0 =================
    proj_step();
    bar_sync(bar, blk, ep); ep++;
    if (blk < 64) softmax_step(out);
    bar_sync(bar, blk, ep); ep++;

    // ================= decode: 31 steps =================
    for (int d = 1; d < TOUT; d++) {
        // phase A: x @ W_ih
        stage16(xd + ((size_t)(bg * 16) << 10), hs);
        __syncthreads();
        f32x4 acc = {0.f, 0.f, 0.f, 0.f};
        #pragma unroll 8
        for (int kk = 0; kk < 1024; kk += 32)
            acc = MFMA16(*(const short8*)(hfp + kk), *(const short8*)(wip + kk), acc);
        __syncthreads();                        // xs fully consumed
        // phase B: h @ W_hh
        stage16(hcur + ((size_t)(bg * 16) << 10), hs);
        __syncthreads();
        #pragma unroll 8
        for (int kk = 0; kk < 1024; kk += 32)
            acc = MFMA16(*(const short8*)(hfp + kk), *(const short8*)(whp + kk), acc);
        gwrite(acc);
        __syncthreads();
        pointwise(d == TOUT - 1);
        bar_sync(bar, blk, ep); ep++;
        ushort* tmp = hcur; hcur = hnxt; hnxt = tmp;

        proj_step();
        bar_sync(bar, blk, ep); ep++;
        if (blk < 64) softmax_step(out + (size_t)d * NE);
        bar_sync(bar, blk, ep); ep++;
    }
}

// ---------------------------------------------------------------------------
extern "C" void kernel_launch(void* const* d_in, const int* in_sizes, int n_in,
                              void* d_out, int out_size, void* d_ws, size_t ws_size,
                              hipStream_t stream)
{
    const float* input = (const float*)d_in[0];   // [128,64,1024]
    const float* h0    = (const float*)d_in[1];
    const float* c0    = (const float*)d_in[2];
    const float* W_ih  = (const float*)d_in[3];   // [4096,1024]
    const float* W_hh  = (const float*)d_in[4];
    const float* b_ih  = (const float*)d_in[5];
    const float* b_hh  = (const float*)d_in[6];
    const float* W_out = (const float*)d_in[7];   // [1024,1024]
    const float* b_out = (const float*)d_in[8];
    float* out = (float*)d_out;                   // [32,64,1024] + h + c

    char* w = (char*)d_ws;
    ushort*    Whh_bf  = (ushort*)   (w + 0);          //  8,388,608 B
    ushort*    Wih_bf  = (ushort*)   (w + 8388608);    //  8,388,608 B
    ushort*    Wout_bf = (ushort*)   (w + 16777216);   //  2,097,152 B
    _Float16*  XgT     = (_Float16*) (w + 18874368);   // 67,108,864 B
    ushort*    hA      = (ushort*)   (w + 85983232);   //    131,072 B
    ushort*    hB      = (ushort*)   (w + 86114304);   //    131,072 B
    ushort*    xd      = (ushort*)   (w + 86245376);   //    131,072 B
    float*     y       = (float*)    (w + 86376448);   //    262,144 B
    unsigned*  bar     = (unsigned*) (w + 86638592);   //     20,480 B

    cvt_bf16<<<dim3(4096), dim3(256), 0, stream>>>(W_ih,  Wih_bf,  NG * HD);
    cvt_bf16<<<dim3(4096), dim3(256), 0, stream>>>(W_hh,  Whh_bf,  NG * HD);
    cvt_bf16<<<dim3(1024), dim3(256), 0, stream>>>(W_out, Wout_bf, HD * HD);
    prep<<<dim3(256), dim3(256), 0, stream>>>(h0, hA, bar);
    gemm_xgt<<<dim3(32, 64), dim3(256), 0, stream>>>(input, Wih_bf, XgT);

    const ushort* a0 = Wih_bf;  const ushort* a1 = Whh_bf;
    const ushort* a2 = Wout_bf; const _Float16* a3 = XgT;
    ushort* a4 = hA; ushort* a5 = hB; ushort* a6 = xd;
    float* a7 = y; unsigned* a8 = bar;
    const float* a9 = b_ih; const float* a10 = b_hh; const float* a11 = b_out;
    const float* a12 = c0;  float* a13 = out;
    void* args[] = {&a0, &a1, &a2, &a3, &a4, &a5, &a6, &a7, &a8,
                    &a9, &a10, &a11, &a12, &a13};
    hipLaunchCooperativeKernel((const void*)lstm_coop, dim3(256), dim3(256),
                               args, 0, stream);
}

// Round 8
// 1887.265 us; speedup vs baseline: 1.8124x; 1.0366x over previous
//
#include <hip/hip_runtime.h>
#include <math.h>

// Problem dims (fixed by reference)
#define SEQ    128
#define BATCH  64
#define HD     1024
#define NG     4096
#define TOUT   32
#define NE     65536      // BATCH*HD
#define CHS    32         // encode steps per chunk
#define MCH    2048       // rows per gemm chunk = CHS*BATCH
#define NHBUF  160        // SEQ + TOUT h buffers (write-once rotation)
#define BAR_WORDS 8192    // 4 groups x 2048 u32

typedef __attribute__((ext_vector_type(8))) short    short8;
typedef __attribute__((ext_vector_type(4))) float    f32x4;
typedef __attribute__((ext_vector_type(4))) _Float16 f16x4;

#define MFMA16(a,b,c) __builtin_amdgcn_mfma_f32_16x16x32_bf16((a),(b),(c),0,0,0)

__device__ __forceinline__ ushort bf16_rne(float x) {
    union { float f; unsigned u; } v; v.f = x;
    unsigned r = v.u + 0x7FFF + ((v.u >> 16) & 1);
    return (ushort)(r >> 16);
}

// ---- device-coherent (agent-scope) accesses: write to L3 point, no fences ----
__device__ __forceinline__ unsigned long long cload64(const void* p) {
    return __hip_atomic_load((const unsigned long long*)p, __ATOMIC_RELAXED,
                             __HIP_MEMORY_SCOPE_AGENT);
}
__device__ __forceinline__ void cstore32(void* p, unsigned v) {
    __hip_atomic_store((unsigned*)p, v, __ATOMIC_RELAXED, __HIP_MEMORY_SCOPE_AGENT);
}
__device__ __forceinline__ void cstore64(void* p, unsigned long long v) {
    __hip_atomic_store((unsigned long long*)p, v, __ATOMIC_RELAXED,
                       __HIP_MEMORY_SCOPE_AGENT);
}
union QF { unsigned long long q; float f[2]; };

// ---------------------------------------------------------------------------
// fp32 -> bf16 (RNE), 4 elems/thread; n % 1024 == 0
// ---------------------------------------------------------------------------
__global__ __launch_bounds__(256) void cvt_bf16(
    const float* __restrict__ src, ushort* __restrict__ dst, int n)
{
    int i = (blockIdx.x * 256 + threadIdx.x) * 4;
    if (i < n) {
        float4 v = *(const float4*)(src + i);
        ushort4 o;
        o.x = bf16_rne(v.x); o.y = bf16_rne(v.y);
        o.z = bf16_rne(v.z); o.w = bf16_rne(v.w);
        *(ushort4*)(dst + i) = o;
    }
}

// prep: h0 -> bf16 into hbuf(0); cbuf = c0; zero barrier region.
__global__ __launch_bounds__(256) void prep(
    const float* __restrict__ h0, const float* __restrict__ c0,
    ushort* __restrict__ h0b, float* __restrict__ cbuf, unsigned* __restrict__ bar)
{
    int i = blockIdx.x * 256 + threadIdx.x;
    h0b[i] = bf16_rne(h0[i]);
    cbuf[i] = c0[i];
    if (blockIdx.x == 0)
        for (int k = threadIdx.x; k < BAR_WORDS; k += 256) bar[k] = 0u;
}

// ---------------------------------------------------------------------------
// Chunk GEMM: XgT[gcol][m] = sum_k A[m][k]*Wih[gcol][k], A bf16 [2048][1024],
// out fp16 transposed (m-pitch 2048). grid (4096/128, 2048/128) = (32,16).
// ---------------------------------------------------------------------------
__global__ __launch_bounds__(256) void gemm_xgt(
    const ushort* __restrict__ A, const ushort* __restrict__ Wih,
    _Float16* __restrict__ XgT)
{
    const int wave = threadIdx.x >> 6, lane = threadIdx.x & 63;
    const int l15 = lane & 15, q8 = (lane >> 4) * 8, r0 = (lane >> 4) * 4;
    const int wr = wave >> 1, wc = wave & 1;
    const int m0 = blockIdx.y * 128 + wr * 64;
    const int n0 = blockIdx.x * 128 + wc * 64;

    const ushort* ap[4];
    const ushort* bp[4];
    #pragma unroll
    for (int f = 0; f < 4; f++) {
        ap[f] = A   + (size_t)(m0 + f * 16 + l15) * 1024 + q8;
        bp[f] = Wih + (size_t)(n0 + f * 16 + l15) * 1024 + q8;
    }

    f32x4 acc[4][4];
    #pragma unroll
    for (int f = 0; f < 4; f++)
        #pragma unroll
        for (int g = 0; g < 4; g++)
            acc[f][g] = (f32x4){0.f, 0.f, 0.f, 0.f};

    for (int kk = 0; kk < 1024; kk += 32) {
        short8 a[4], b[4];
        #pragma unroll
        for (int f = 0; f < 4; f++) {
            a[f] = *(const short8*)(ap[f] + kk);
            b[f] = *(const short8*)(bp[f] + kk);
        }
        #pragma unroll
        for (int f = 0; f < 4; f++)
            #pragma unroll
            for (int g = 0; g < 4; g++)
                acc[f][g] = MFMA16(a[f], b[g], acc[f][g]);
    }

    #pragma unroll
    for (int f = 0; f < 4; f++) {
        const int mbase = m0 + f * 16 + r0;
        #pragma unroll
        for (int g = 0; g < 4; g++) {
            const int gcol = n0 + g * 16 + l15;
            *(f16x4*)(XgT + (size_t)gcol * MCH + mbase) =
                __builtin_convertvector(acc[f][g], f16x4);
        }
    }
}

// ---------------------------------------------------------------------------
// Per-group (64-block) fence-free barrier: 8x8 arrival tree + per-block
// release lines; epochs monotonic across the whole sequence of launches.
// barg layout (u32): sub[s]@s*64 (s=0..7), root@512, release[m]@576+m*16.
// ---------------------------------------------------------------------------
__device__ __forceinline__ void gbar(unsigned* barg, int m, unsigned epoch) {
    asm volatile("s_waitcnt vmcnt(0) lgkmcnt(0)" ::: "memory");
    __syncthreads();
    if (threadIdx.x < 64) {
        bool fin = false;
        if (threadIdx.x == 0) {
            unsigned* sub = barg + (m >> 3) * 64;
            if (__hip_atomic_fetch_add(sub, 1u, __ATOMIC_RELAXED,
                                       __HIP_MEMORY_SCOPE_AGENT) == 7u) {
                __hip_atomic_store(sub, 0u, __ATOMIC_RELAXED, __HIP_MEMORY_SCOPE_AGENT);
                if (__hip_atomic_fetch_add(barg + 512, 1u, __ATOMIC_RELAXED,
                                           __HIP_MEMORY_SCOPE_AGENT) == 7u) {
                    __hip_atomic_store(barg + 512, 0u, __ATOMIC_RELAXED,
                                       __HIP_MEMORY_SCOPE_AGENT);
                    fin = true;
                }
            }
        }
        if (__ballot(fin) != 0ull)
            cstore32(barg + 576 + threadIdx.x * 16, epoch);
        if (threadIdx.x == 0) {
            while (__hip_atomic_load(barg + 576 + m * 16, __ATOMIC_RELAXED,
                                     __HIP_MEMORY_SCOPE_AGENT) < epoch)
                __builtin_amdgcn_s_sleep(1);
        }
    }
    __syncthreads();
}

// ---------------------------------------------------------------------------
// Stage 16x1024 bf16 tile via NORMAL cached loads (write-once buffers make
// this safe); 8 loads batched in regs then 8 LDS stores (pitch 1032).
// ---------------------------------------------------------------------------
__device__ __forceinline__ void stageN(const ushort* __restrict__ src,
                                       ushort* __restrict__ dst)
{
    const int tid = threadIdx.x;
    short8 t[8];
    #pragma unroll
    for (int i = 0; i < 8; i++) {
        int idx = i * 256 + tid;
        t[i] = *(const short8*)(src + ((size_t)(idx >> 7) << 10) + (idx & 127) * 8);
    }
    #pragma unroll
    for (int i = 0; i < 8; i++) {
        int idx = i * 256 + tid;
        *(short8*)&dst[(idx >> 7) * 1032 + (idx & 127) * 8] = t[i];
    }
}
__device__ __forceinline__ void stage2(const ushort* __restrict__ s0, ushort* __restrict__ d0,
                                       const ushort* __restrict__ s1, ushort* __restrict__ d1)
{
    const int tid = threadIdx.x;
    short8 a[8], b[8];
    #pragma unroll
    for (int i = 0; i < 8; i++) {
        int idx = i * 256 + tid;
        a[i] = *(const short8*)(s0 + ((size_t)(idx >> 7) << 10) + (idx & 127) * 8);
        b[i] = *(const short8*)(s1 + ((size_t)(idx >> 7) << 10) + (idx & 127) * 8);
    }
    #pragma unroll
    for (int i = 0; i < 8; i++) {
        int idx = i * 256 + tid;
        *(short8*)&d0[(idx >> 7) * 1032 + (idx & 127) * 8] = a[i];
        *(short8*)&d1[(idx >> 7) * 1032 + (idx & 127) * 8] = b[i];
    }
}

// ---------------------------------------------------------------------------
// Persistent cooperative LSTM segment. Block (bg=blk>>6, ug=blk&63):
// cell = 16-batch x 16-unit tile (wave = gate type); proj = 16x16 y patch
// (wave split-K); softmax: blocks with (blk&63)<16, row = bg*16+m.
// The 4 bg groups are fully independent -> per-group barriers.
// h/xd buffers rotate (write-once) in REVERSE address order.
// ---------------------------------------------------------------------------
__global__ __launch_bounds__(256, 1) void lstm_coop(
    const ushort* __restrict__ Wih, const ushort* __restrict__ Whh,
    const ushort* __restrict__ Wout, const _Float16* __restrict__ XgT,
    ushort* __restrict__ Hbase, ushort* __restrict__ Xdbase,
    float* __restrict__ y, unsigned* __restrict__ bar,
    const float* __restrict__ b_ih, const float* __restrict__ b_hh,
    const float* __restrict__ b_out, float* __restrict__ cbuf,
    float* __restrict__ out, int t0, int nsteps, int dodec, unsigned ep0)
{
    __shared__ ushort hs0[16 * 1032];
    __shared__ ushort hs1[16 * 1032];
    __shared__ float  gbuf[1088];

    const int blk  = blockIdx.x;
    const int bg   = blk >> 6, m = blk & 63, ug = m;
    const int tid  = threadIdx.x;
    const int wave = tid >> 6, lane = tid & 63;
    const int l15  = lane & 15, q8 = (lane >> 4) * 8, r0 = (lane >> 4) * 4;
    const int b    = tid >> 4, u = tid & 15;

    unsigned* barg = bar + bg * 2048;

    const int gi = ug * 16 + u;
    const float bs0 = b_ih[gi]        + b_hh[gi];
    const float bs1 = b_ih[1024 + gi] + b_hh[1024 + gi];
    const float bs2 = b_ih[2048 + gi] + b_hh[2048 + gi];
    const float bs3 = b_ih[3072 + gi] + b_hh[3072 + gi];
    const int cidx = ((bg * 16 + b) << 10) + gi;
    float c_reg = cbuf[cidx];

    const ushort* wip = Wih + (((size_t)(wave * 1024 + ug * 16 + l15)) << 10) + q8;
    const ushort* whp = Whh + (((size_t)(wave * 1024 + ug * 16 + l15)) << 10) + q8;
    const ushort* wop = Wout + (((size_t)(ug * 16 + l15)) << 10) + wave * 256 + q8;
    const _Float16* xgp = XgT + (size_t)(wave * 1024 + ug * 16 + l15) * MCH
                              + bg * 16 + r0;
    const ushort* f0 = hs0 + l15 * 1032 + q8;
    const ushort* f1 = hs1 + l15 * 1032 + q8;

    unsigned ep = ep0;

    auto hbuf = [&](int t) -> ushort* {
        return Hbase + (size_t)(NHBUF - 1 - t) * NE;
    };
    auto xdbuf = [&](int d) -> ushort* {
        return Xdbase + (size_t)(TOUT - 1 - d) * NE;
    };

    auto gwrite = [&](f32x4 acc) {
        #pragma unroll
        for (int r = 0; r < 4; r++)
            gbuf[(r0 + r) * 68 + wave * 16 + l15] = acc[r];
    };

    auto pointwise = [&](ushort* hnxt, bool fin) {
        float ig = gbuf[b * 68 + u]      + bs0;
        float fg = gbuf[b * 68 + 16 + u] + bs1;
        float gg = gbuf[b * 68 + 32 + u] + bs2;
        float og = gbuf[b * 68 + 48 + u] + bs3;
        float si = 1.f / (1.f + expf(-ig));
        float sf = 1.f / (1.f + expf(-fg));
        float so = 1.f / (1.f + expf(-og));
        float tg = tanhf(gg);
        float cn = sf * c_reg + si * tg;
        c_reg = cn;
        float hn = so * tanhf(cn);
        ushort hb16 = bf16_rne(hn);
        unsigned hi = (unsigned)(ushort)__shfl_down((int)hb16, 1);
        if ((u & 1) == 0)
            cstore32((void*)(hnxt + cidx), (unsigned)hb16 | (hi << 16));
        if (fin) {
            out[(size_t)TOUT * NE + cidx]       = hn;
            out[(size_t)(TOUT + 1) * NE + cidx] = cn;
        }
    };

    auto proj_step = [&](const ushort* hcur) {
        stageN(hcur + ((size_t)(bg * 16) << 10), hs0);
        __syncthreads();
        const ushort* hpp = hs0 + l15 * 1032 + wave * 256 + q8;
        f32x4 ac = {0.f, 0.f, 0.f, 0.f};
        #pragma unroll
        for (int kk = 0; kk < 256; kk += 32)
            ac = MFMA16(*(const short8*)(hpp + kk), *(const short8*)(wop + kk), ac);
        #pragma unroll
        for (int r = 0; r < 4; r++)
            gbuf[wave * 256 + (r0 + r) * 16 + l15] = ac[r];
        __syncthreads();
        float v = gbuf[b * 16 + u] + gbuf[256 + b * 16 + u]
                + gbuf[512 + b * 16 + u] + gbuf[768 + b * 16 + u]
                + b_out[ug * 16 + u];
        union { float f; unsigned uu; } cv; cv.f = v;
        cstore32(y + (size_t)(bg * 16 + b) * 1024 + ug * 16 + u, cv.uu);
    };

    auto softmax_step = [&](float* __restrict__ outp, ushort* __restrict__ xdn) {
        const int row = bg * 16 + m;   // only called when m < 16
        QF a, c;
        a.q = cload64(y + (size_t)row * 1024 + tid * 4);
        c.q = cload64(y + (size_t)row * 1024 + tid * 4 + 2);
        float v0 = a.f[0], v1 = a.f[1], v2 = c.f[0], v3 = c.f[1];
        gbuf[tid] = fmaxf(fmaxf(v0, v1), fmaxf(v2, v3));
        __syncthreads();
        for (int st = 128; st > 0; st >>= 1) {
            if (tid < st) gbuf[tid] = fmaxf(gbuf[tid], gbuf[tid + st]);
            __syncthreads();
        }
        float mx = gbuf[0];
        __syncthreads();
        gbuf[tid] = expf(v0 - mx) + expf(v1 - mx) + expf(v2 - mx) + expf(v3 - mx);
        __syncthreads();
        for (int st = 128; st > 0; st >>= 1) {
            if (tid < st) gbuf[tid] += gbuf[tid + st];
            __syncthreads();
        }
        float lse = mx + logf(gbuf[0]);
        float4 o = make_float4(v0 - lse, v1 - lse, v2 - lse, v3 - lse);
        *(float4*)(outp + (size_t)row * 1024 + tid * 4) = o;
        unsigned lo = (unsigned)bf16_rne(o.x) | ((unsigned)bf16_rne(o.y) << 16);
        unsigned hi = (unsigned)bf16_rne(o.z) | ((unsigned)bf16_rne(o.w) << 16);
        cstore64(xdn + (size_t)row * 1024 + tid * 4,
                 (unsigned long long)lo | ((unsigned long long)hi << 32));
    };

    // ================= encode segment =================
    for (int s = 0; s < nsteps; s++) {
        const int t = t0 + s;
        f16x4 xg4 = *(const f16x4*)(xgp + (size_t)s * 64);
        stageN(hbuf(t) + ((size_t)(bg * 16) << 10), hs0);
        __syncthreads();
        f32x4 a0 = __builtin_convertvector(xg4, f32x4);
        f32x4 a1 = {0.f, 0.f, 0.f, 0.f};
        #pragma unroll 8
        for (int kk = 0; kk < 512; kk += 32)
            a0 = MFMA16(*(const short8*)(f0 + kk), *(const short8*)(whp + kk), a0);
        #pragma unroll 8
        for (int kk = 512; kk < 1024; kk += 32)
            a1 = MFMA16(*(const short8*)(f0 + kk), *(const short8*)(whp + kk), a1);
        gwrite(a0 + a1);
        __syncthreads();
        pointwise(hbuf(t + 1), false);
        gbar(barg, m, ep); ep++;
    }

    if (!dodec) {
        cbuf[cidx] = c_reg;   // spill recurrent c for the next segment
        return;
    }

    // ================= out0 =================
    proj_step(hbuf(SEQ));
    gbar(barg, m, ep); ep++;
    if (m < 16) softmax_step(out, xdbuf(0));
    gbar(barg, m, ep); ep++;

    // ================= decode: 31 steps =================
    for (int d = 1; d < TOUT; d++) {
        stage2(xdbuf(d - 1) + ((size_t)(bg * 16) << 10), hs0,
               hbuf(SEQ + d - 1) + ((size_t)(bg * 16) << 10), hs1);
        __syncthreads();
        f32x4 x0 = {0.f,0.f,0.f,0.f}, x1 = {0.f,0.f,0.f,0.f};
        f32x4 h0a = {0.f,0.f,0.f,0.f}, h1a = {0.f,0.f,0.f,0.f};
        #pragma unroll 8
        for (int kk = 0; kk < 512; kk += 32) {
            x0  = MFMA16(*(const short8*)(f0 + kk), *(const short8*)(wip + kk), x0);
            h0a = MFMA16(*(const short8*)(f1 + kk), *(const short8*)(whp + kk), h0a);
        }
        #pragma unroll 8
        for (int kk = 512; kk < 1024; kk += 32) {
            x1  = MFMA16(*(const short8*)(f0 + kk), *(const short8*)(wip + kk), x1);
            h1a = MFMA16(*(const short8*)(f1 + kk), *(const short8*)(whp + kk), h1a);
        }
        gwrite((x0 + x1) + (h0a + h1a));
        __syncthreads();
        pointwise(hbuf(SEQ + d), d == TOUT - 1);
        gbar(barg, m, ep); ep++;

        proj_step(hbuf(SEQ + d));
        gbar(barg, m, ep); ep++;
        if (m < 16) softmax_step(out + (size_t)d * NE, xdbuf(d));
        gbar(barg, m, ep); ep++;
    }
}

// ---------------------------------------------------------------------------
extern "C" void kernel_launch(void* const* d_in, const int* in_sizes, int n_in,
                              void* d_out, int out_size, void* d_ws, size_t ws_size,
                              hipStream_t stream)
{
    const float* input = (const float*)d_in[0];   // [128,64,1024]
    const float* h0    = (const float*)d_in[1];
    const float* c0    = (const float*)d_in[2];
    const float* W_ih  = (const float*)d_in[3];   // [4096,1024]
    const float* W_hh  = (const float*)d_in[4];
    const float* b_ih  = (const float*)d_in[5];
    const float* b_hh  = (const float*)d_in[6];
    const float* W_out = (const float*)d_in[7];   // [1024,1024]
    const float* b_out = (const float*)d_in[8];
    float* out = (float*)d_out;                   // [32,64,1024] + h + c

    char* w = (char*)d_ws;                                    // bytes
    ushort*    Whh_bf = (ushort*)   (w + 0);                  //  8,388,608
    ushort*    Wih_bf = (ushort*)   (w + 8388608);            //  8,388,608
    ushort*    Wout_bf= (ushort*)   (w + 16777216);           //  2,097,152
    _Float16*  XgT    = (_Float16*) (w + 18874368);           // 16,777,216
    ushort*    Xbc    = (ushort*)   (w + 35651584);           //  4,194,304
    ushort*    Hbase  = (ushort*)   (w + 39845888);           // 20,971,520
    ushort*    Xdbase = (ushort*)   (w + 60817408);           //  4,194,304
    float*     y      = (float*)    (w + 65011712);           //    262,144
    float*     cbuf   = (float*)    (w + 65273856);           //    262,144
    unsigned*  bar    = (unsigned*) (w + 65536000);           //     32,768
    // total ~65.6 MB (proven budget: 86.7 MB in round 7)

    cvt_bf16<<<dim3(4096), dim3(256), 0, stream>>>(W_ih,  Wih_bf,  NG * HD);
    cvt_bf16<<<dim3(4096), dim3(256), 0, stream>>>(W_hh,  Whh_bf,  NG * HD);
    cvt_bf16<<<dim3(1024), dim3(256), 0, stream>>>(W_out, Wout_bf, HD * HD);
    // hbuf(0) = Hbase + (NHBUF-1)*NE
    prep<<<dim3(256), dim3(256), 0, stream>>>(
        h0, c0, Hbase + (size_t)(NHBUF - 1) * NE, cbuf, bar);

    for (int ch = 0; ch < SEQ / CHS; ch++) {
        cvt_bf16<<<dim3(2048), dim3(256), 0, stream>>>(
            input + (size_t)ch * CHS * NE, Xbc, CHS * NE);
        gemm_xgt<<<dim3(32, 16), dim3(256), 0, stream>>>(Xbc, Wih_bf, XgT);

        const ushort* a0 = Wih_bf;  const ushort* a1 = Whh_bf;
        const ushort* a2 = Wout_bf; const _Float16* a3 = XgT;
        ushort* a4 = Hbase; ushort* a5 = Xdbase;
        float* a6 = y; unsigned* a7 = bar;
        const float* a8 = b_ih; const float* a9 = b_hh; const float* a10 = b_out;
        float* a11 = cbuf; float* a12 = out;
        int t0 = ch * CHS, ns = CHS, dodec = (ch == SEQ / CHS - 1) ? 1 : 0;
        unsigned ep0 = 1u + (unsigned)(ch * CHS);
        void* args[] = {&a0, &a1, &a2, &a3, &a4, &a5, &a6, &a7,
                        &a8, &a9, &a10, &a11, &a12, &t0, &ns, &dodec, &ep0};
        hipLaunchCooperativeKernel((const void*)lstm_coop, dim3(256), dim3(256),
                                   args, 0, stream);
    }
}